// Round 3
// baseline (647.224 us; speedup 1.0000x reference)
//
#include <hip/hip_runtime.h>
#include <stdint.h>

#define N_NODES 100000
#define DIM     128
#define RANK    8
#define N_REL   16
#define N_EDGE  250000

typedef __attribute__((ext_vector_type(8))) short  short8v;
typedef __attribute__((ext_vector_type(4))) float  float4v;

__device__ inline unsigned short f2bf(float f) {
    union { float f; unsigned u; } v; v.f = f;
    unsigned r = v.u + 0x7fffu + ((v.u >> 16) & 1u);   // round-nearest-even
    return (unsigned short)(r >> 16);
}
__device__ inline float bf2f(unsigned short h) {
    union { unsigned u; float f; } v; v.u = ((unsigned)h) << 16;
    return v.f;
}

// ---------------------------------------------------------------------------
// Weight / embedding fp32 -> bf16 conversion + layout build (once per launch).
// Output (shorts):
//   [0,32768)       WyB [256][128] : rows 0-127 = W[out][in];
//                   rows 128+c (c=rt*8+k) : col d = B_emb[rt][d*8+k]  (BcatT)
//   [32768,65536)   W1b [256][128]
//   [65536,131072)  W2b [256][256]
//   [131072,163840) W3b [128][256]
//   [163840,180224) Ab  [rt][d][k]  (natural A_emb layout)
// ---------------------------------------------------------------------------
__global__ __launch_bounds__(256) void wcvt_kernel(
    const float* __restrict__ W,  const float* __restrict__ W1,
    const float* __restrict__ W2, const float* __restrict__ W3,
    const float* __restrict__ Ae, const float* __restrict__ Be,
    unsigned short* __restrict__ out)
{
    int i = blockIdx.x * blockDim.x + threadIdx.x;
    if (i >= 180224) return;
    float v;
    if      (i <  16384) v = W[i];
    else if (i <  32768) {
        int j = i - 16384; int c = j >> 7, d = j & 127;
        v = Be[(c >> 3) * 1024 + d * 8 + (c & 7)];
    }
    else if (i <  65536) v = W1[i - 32768];
    else if (i < 131072) v = W2[i - 65536];
    else if (i < 163840) v = W3[i - 131072];
    else                 v = Ae[i - 163840];
    out[i] = f2bf(v);
}

// ---------------------------------------------------------------------------
// Counting sort of edges by dst
// ---------------------------------------------------------------------------
__global__ __launch_bounds__(256) void hist_kernel(
    const int* __restrict__ eidx, int* __restrict__ deg)
{
    int e = blockIdx.x * 256 + threadIdx.x;
    if (e < N_EDGE) atomicAdd(&deg[eidx[N_EDGE + e]], 1);
}

#define SCAN_THREADS 1024
#define SCAN_CHUNK   98   // 1024*98 = 100352 >= N_NODES

__global__ __launch_bounds__(1024) void scan_kernel(
    const int* __restrict__ deg, int* __restrict__ offsets, int* __restrict__ wo)
{
    __shared__ int wsum[16];
    const int t = threadIdx.x;
    const int lane = t & 63, wid = t >> 6;
    const int base = t * SCAN_CHUNK;
    int sum = 0;
    #pragma unroll 1
    for (int i = 0; i < SCAN_CHUNK; ++i) {
        int idx = base + i;
        sum += (idx < N_NODES) ? deg[idx] : 0;
    }
    int inc = sum;
    #pragma unroll
    for (int off = 1; off < 64; off <<= 1) {
        int v = __shfl_up(inc, off);
        if (lane >= off) inc += v;
    }
    if (lane == 63) wsum[wid] = inc;
    __syncthreads();
    if (wid == 0) {
        int v = (lane < 16) ? wsum[lane] : 0;
        int winc = v;
        #pragma unroll
        for (int off = 1; off < 16; off <<= 1) {
            int u = __shfl_up(winc, off);
            if (lane >= off) winc += u;
        }
        if (lane < 16) wsum[lane] = winc - v;   // exclusive wave base
    }
    __syncthreads();
    int running = wsum[wid] + (inc - sum);      // exclusive prefix of this thread
    #pragma unroll 1
    for (int i = 0; i < SCAN_CHUNK; ++i) {
        int idx = base + i;
        if (idx < N_NODES) {
            int v = deg[idx];
            offsets[idx] = running;
            wo[idx]      = running;
            running += v;
        }
    }
    if (t == 0) offsets[N_NODES] = N_EDGE;
}

__global__ __launch_bounds__(256) void scatter_kernel(
    const int* __restrict__ eidx, int* __restrict__ wo, int* __restrict__ sorted)
{
    int e = blockIdx.x * 256 + threadIdx.x;
    if (e < N_EDGE) {
        int pos = atomicAdd(&wo[eidx[N_EDGE + e]], 1);
        sorted[pos] = e;
    }
}

// ---------------------------------------------------------------------------
// Aggregation: one wave per dst node; lane owns channels {2l, 2l+1}.
// Per incoming edge: msg = y[src] + A[rt] @ Bj_all[src,rt]; accumulate in regs.
// Epilogue: h0 = (1+eps)*x[node] + acc   (bf16 store)
// ---------------------------------------------------------------------------
__global__ __launch_bounds__(256) void aggr_kernel(
    const float*          __restrict__ x,
    const int*            __restrict__ eidx,
    const int*            __restrict__ etype,
    const unsigned short* __restrict__ ybj,     // [N][256]: 0-127 y, 128-255 Bj
    const unsigned short* __restrict__ Ab,      // [rt][d][k]
    const int*            __restrict__ offsets,
    const int*            __restrict__ sorted,
    const float*          __restrict__ epsp,
    unsigned short*       __restrict__ h0)      // [N][128]
{
    const int lane = threadIdx.x & 63;
    const int node = blockIdx.x * 4 + (threadIdx.x >> 6);
    if (node >= N_NODES) return;

    const int beg = offsets[node], end = offsets[node + 1];
    float acc0 = 0.f, acc1 = 0.f;

    for (int i = beg; i < end; ++i) {
        const int eid = sorted[i];
        const int src = eidx[eid];
        const int rt  = etype[eid];

        short8v bj = *reinterpret_cast<const short8v*>(
            ybj + (size_t)src * 256 + 128 + rt * 8);          // wave-uniform 16B
        const unsigned short* ap = Ab + rt * 1024 + 16 * lane; // L1-resident (32KB)
        short8v a0 = *reinterpret_cast<const short8v*>(ap);
        short8v a1 = *reinterpret_cast<const short8v*>(ap + 8);
        unsigned yv = *reinterpret_cast<const unsigned*>(
            ybj + (size_t)src * 256 + 2 * lane);               // coalesced 256B

        float ad0 = 0.f, ad1 = 0.f;
        #pragma unroll
        for (int k = 0; k < 8; ++k) {
            float p = bf2f((unsigned short)bj[k]);
            ad0 += bf2f((unsigned short)a0[k]) * p;
            ad1 += bf2f((unsigned short)a1[k]) * p;
        }
        acc0 += bf2f((unsigned short)(yv & 0xffffu)) + ad0;
        acc1 += bf2f((unsigned short)(yv >> 16)) + ad1;
    }

    const float s1 = 1.0f + epsp[0];
    float2 xv = *reinterpret_cast<const float2*>(x + (size_t)node * DIM + 2 * lane);
    unsigned o = (unsigned)f2bf(s1 * xv.x + acc0)
               | ((unsigned)f2bf(s1 * xv.y + acc1) << 16);
    *reinterpret_cast<unsigned*>(h0 + (size_t)node * DIM + 2 * lane) = o;
}

// ---------------------------------------------------------------------------
// Strip GEMM: C[M x NOUT] = act(A[M x K] @ Wb[NOUT x K]^T + bias)
// One wave: 2 strips of 16 rows, all NOUT cols. A-frags in regs, B from L2.
// AMODE: 0 = A fp32, 2 = A bf16.  OMODE: 0 = bf16, 1 = bf16 relu+bias, 2 = fp32 +bias
// ---------------------------------------------------------------------------
template<int K, int NOUT, int AMODE, int OMODE>
__global__ __launch_bounds__(256) void strip_gemm(
    const void*           __restrict__ Aptr,
    const unsigned short* __restrict__ Wb,
    const float*          __restrict__ bias,
    void*                 __restrict__ Out)
{
    constexpr int NSTRIP = 2;
    constexpr int KT = K / 32;
    constexpr int NT = NOUT / 16;
    constexpr int NSTRIPS_TOT = N_NODES / 16;   // 6250

    const int wave = threadIdx.x >> 6;
    const int lane = threadIdx.x & 63;
    const int job  = blockIdx.x * 4 + wave;
    const int strip0 = job * NSTRIP;
    if (strip0 >= NSTRIPS_TOT) return;

    const int row16 = lane & 15;
    const int kgrp  = lane >> 4;

    short8v afrag[NSTRIP][KT];
    #pragma unroll
    for (int s = 0; s < NSTRIP; ++s) {
        const int m = (strip0 + s) * 16 + row16;
        #pragma unroll
        for (int kt = 0; kt < KT; ++kt) {
            const int k0 = kt * 32 + kgrp * 8;
            if constexpr (AMODE == 2) {
                afrag[s][kt] = *reinterpret_cast<const short8v*>(
                    (const unsigned short*)Aptr + (size_t)m * K + k0);
            } else {
                const float* ap = (const float*)Aptr + (size_t)m * K + k0;
                float4v v0 = *reinterpret_cast<const float4v*>(ap);
                float4v v1 = *reinterpret_cast<const float4v*>(ap + 4);
                short8v f;
                #pragma unroll
                for (int j = 0; j < 4; ++j) {
                    f[j]     = (short)f2bf(v0[j]);
                    f[4 + j] = (short)f2bf(v1[j]);
                }
                afrag[s][kt] = f;
            }
        }
    }

    #pragma unroll 2
    for (int nt = 0; nt < NT; ++nt) {
        const int n = nt * 16 + row16;
        float4v acc[NSTRIP];
        #pragma unroll
        for (int s = 0; s < NSTRIP; ++s) acc[s] = (float4v){0.f, 0.f, 0.f, 0.f};

        #pragma unroll
        for (int kt = 0; kt < KT; ++kt) {
            short8v bfrag = *reinterpret_cast<const short8v*>(
                Wb + (size_t)n * K + kt * 32 + kgrp * 8);
            #pragma unroll
            for (int s = 0; s < NSTRIP; ++s)
                acc[s] = __builtin_amdgcn_mfma_f32_16x16x32_bf16(
                    afrag[s][kt], bfrag, acc[s], 0, 0, 0);
        }

        const float bv = (OMODE != 0) ? bias[n] : 0.f;
        #pragma unroll
        for (int s = 0; s < NSTRIP; ++s) {
            #pragma unroll
            for (int r = 0; r < 4; ++r) {
                const int m = (strip0 + s) * 16 + kgrp * 4 + r;
                float v = acc[s][r];
                if constexpr (OMODE == 1) v = fmaxf(v + bv, 0.f);
                if constexpr (OMODE == 2) v = v + bv;
                if constexpr (OMODE == 2)
                    ((float*)Out)[(size_t)m * NOUT + n] = v;
                else
                    ((unsigned short*)Out)[(size_t)m * NOUT + n] = f2bf(v);
            }
        }
    }
}

// ---------------------------------------------------------------------------
// Launch
// ---------------------------------------------------------------------------
extern "C" void kernel_launch(void* const* d_in, const int* in_sizes, int n_in,
                              void* d_out, int out_size, void* d_ws, size_t ws_size,
                              hipStream_t stream)
{
    const float* x     = (const float*)d_in[0];
    const int*   eidx  = (const int*)  d_in[1];
    const int*   etype = (const int*)  d_in[2];
    const float* W     = (const float*)d_in[3];
    const float* eps   = (const float*)d_in[4];
    const float* A_emb = (const float*)d_in[5];
    const float* B_emb = (const float*)d_in[6];
    const float* W1    = (const float*)d_in[7];
    const float* b1    = (const float*)d_in[8];
    const float* W2    = (const float*)d_in[9];
    const float* b2    = (const float*)d_in[10];
    const float* W3    = (const float*)d_in[11];
    const float* b3    = (const float*)d_in[12];

    char* wsb = (char*)d_ws;
    // ws layout (lifetime-overlapped), total ~102.8 MB:
    //   [0, 51.2MB)        : ybj bf16 [N][256]   -> later h1 bf16 [N][256]
    //   [51.2MB, 76.8MB)   : h0 bf16 [N][128]    -> overwritten by h2 lower half
    //   [76.8MB, 79.0MB)   : deg/offsets/wo/sorted (dead before h2 is written)
    //   [51.2MB, 102.4MB)  : h2 bf16 [N][256]    (written step 9, after all above dead)
    //   [102.4MB, +360KB)  : bf16 weights/embeddings
    unsigned short* ybj  = (unsigned short*)(wsb);
    unsigned short* h1   = (unsigned short*)(wsb);
    unsigned short* h0   = (unsigned short*)(wsb + 51200000);
    unsigned short* h2   = (unsigned short*)(wsb + 51200000);
    int*            deg     = (int*)(wsb + 76800000);
    int*            offsets = (int*)(wsb + 76800000 + 400000);
    int*            wo      = (int*)(wsb + 76800000 + 800004);
    int*            sorted  = (int*)(wsb + 76800000 + 1200004);
    unsigned short* wts  = (unsigned short*)(wsb + 102400000);

    unsigned short* WyB = wts;
    unsigned short* W1b = wts + 32768;
    unsigned short* W2b = wts + 65536;
    unsigned short* W3b = wts + 131072;
    unsigned short* Ab  = wts + 163840;

    // 1) build bf16 weights / fused [W; BcatT] / A table
    wcvt_kernel<<<704, 256, 0, stream>>>(W, W1, W2, W3, A_emb, B_emb, wts);

    // 2) zero degree counters
    hipMemsetAsync(deg, 0, N_NODES * sizeof(int), stream);

    // 3) fused node GEMM: ybj[n] = [ x@W.T | x@Bcat ]   (bf16)
    strip_gemm<128, 256, 0, 0><<<782, 256, 0, stream>>>(x, WyB, nullptr, ybj);

    // 4-6) counting sort of edges by dst
    hist_kernel   <<<977, 256, 0, stream>>>(eidx, deg);
    scan_kernel   <<<1, SCAN_THREADS, 0, stream>>>(deg, offsets, wo);
    scatter_kernel<<<977, 256, 0, stream>>>(eidx, wo, sorted);

    // 7) aggregate + GIN update -> h0 (bf16)
    aggr_kernel<<<25000, 256, 0, stream>>>(x, eidx, etype, ybj, Ab,
                                           offsets, sorted, eps, h0);

    // 8) h1 = relu(h0 @ W1.T + b1)
    strip_gemm<128, 256, 2, 1><<<782, 256, 0, stream>>>(h0, W1b, b1, h1);

    // 9) h2 = relu(h1 @ W2.T + b2)
    strip_gemm<256, 256, 2, 1><<<782, 256, 0, stream>>>(h1, W2b, b2, h2);

    // 10) out = h2 @ W3.T + b3   (fp32)
    strip_gemm<256, 128, 2, 2><<<782, 256, 0, stream>>>(h2, W3b, b3, d_out);
}

// Round 4
// 405.124 us; speedup vs baseline: 1.5976x; 1.5976x over previous
//
#include <hip/hip_runtime.h>
#include <stdint.h>

#define N_NODES 100000
#define DIM     128
#define RANK    8
#define N_REL   16
#define N_EDGE  250000

#define SCAN_BLOCKS 391   // ceil(N_NODES / 256)

typedef __attribute__((ext_vector_type(8))) short  short8v;
typedef __attribute__((ext_vector_type(4))) float  float4v;

__device__ inline unsigned short f2bf(float f) {
    union { float f; unsigned u; } v; v.f = f;
    unsigned r = v.u + 0x7fffu + ((v.u >> 16) & 1u);   // round-nearest-even
    return (unsigned short)(r >> 16);
}
__device__ inline float bf2f(unsigned short h) {
    union { unsigned u; float f; } v; v.u = ((unsigned)h) << 16;
    return v.f;
}

// ---------------------------------------------------------------------------
// Weight / embedding fp32 -> bf16 conversion + layout build (once per launch).
// Output (shorts):
//   [0,32768)       WyB [256][128] : rows 0-127 = W[out][in];
//                   rows 128+c (c=rt*8+k) : col d = B_emb[rt][d*8+k]  (BcatT)
//   [32768,65536)   W1b [256][128]
//   [65536,131072)  W2b [256][256]
//   [131072,163840) W3b [128][256]
//   [163840,180224) Ab  [rt][d][k]  (natural A_emb layout)
// ---------------------------------------------------------------------------
__global__ __launch_bounds__(256) void wcvt_kernel(
    const float* __restrict__ W,  const float* __restrict__ W1,
    const float* __restrict__ W2, const float* __restrict__ W3,
    const float* __restrict__ Ae, const float* __restrict__ Be,
    unsigned short* __restrict__ out)
{
    int i = blockIdx.x * blockDim.x + threadIdx.x;
    if (i >= 180224) return;
    float v;
    if      (i <  16384) v = W[i];
    else if (i <  32768) {
        int j = i - 16384; int c = j >> 7, d = j & 127;
        v = Be[(c >> 3) * 1024 + d * 8 + (c & 7)];
    }
    else if (i <  65536) v = W1[i - 32768];
    else if (i < 131072) v = W2[i - 65536];
    else if (i < 163840) v = W3[i - 131072];
    else                 v = Ae[i - 163840];
    out[i] = f2bf(v);
}

// ---------------------------------------------------------------------------
// Counting sort of edges by dst
// ---------------------------------------------------------------------------
__global__ __launch_bounds__(256) void hist_kernel(
    const int* __restrict__ eidx, int* __restrict__ deg)
{
    int e = blockIdx.x * 256 + threadIdx.x;
    if (e < N_EDGE) atomicAdd(&deg[eidx[N_EDGE + e]], 1);
}

// Two-level scan: partial block sums -> scan of block sums -> final scan.
__global__ __launch_bounds__(256) void scan_part_kernel(
    const int* __restrict__ deg, int* __restrict__ bsum)
{
    const int idx  = blockIdx.x * 256 + threadIdx.x;
    const int lane = threadIdx.x & 63, wid = threadIdx.x >> 6;
    __shared__ int ws[4];
    int v = (idx < N_NODES) ? deg[idx] : 0;
    #pragma unroll
    for (int off = 1; off < 64; off <<= 1) v += __shfl_xor(v, off);
    if (lane == 0) ws[wid] = v;
    __syncthreads();
    if (threadIdx.x == 0) bsum[blockIdx.x] = ws[0] + ws[1] + ws[2] + ws[3];
}

__global__ __launch_bounds__(512) void scan_bsum_kernel(
    const int* __restrict__ bsum, int* __restrict__ bpre)
{
    const int t = threadIdx.x;
    const int lane = t & 63, wid = t >> 6;
    __shared__ int ws[8];
    int v = (t < SCAN_BLOCKS) ? bsum[t] : 0;
    int inc = v;
    #pragma unroll
    for (int off = 1; off < 64; off <<= 1) {
        int u = __shfl_up(inc, off);
        if (lane >= off) inc += u;
    }
    if (lane == 63) ws[wid] = inc;
    __syncthreads();
    if (wid == 0) {
        int u = (lane < 8) ? ws[lane] : 0;
        int winc = u;
        #pragma unroll
        for (int off = 1; off < 8; off <<= 1) {
            int w = __shfl_up(winc, off);
            if (lane >= off) winc += w;
        }
        if (lane < 8) ws[lane] = winc - u;   // exclusive wave base
    }
    __syncthreads();
    if (t < SCAN_BLOCKS) bpre[t] = ws[wid] + (inc - v);
}

__global__ __launch_bounds__(256) void scan_final_kernel(
    const int* __restrict__ deg, const int* __restrict__ bpre,
    int* __restrict__ offsets, int* __restrict__ wo)
{
    const int idx  = blockIdx.x * 256 + threadIdx.x;
    const int lane = threadIdx.x & 63, wid = threadIdx.x >> 6;
    __shared__ int ws[4];
    int v = (idx < N_NODES) ? deg[idx] : 0;
    int inc = v;
    #pragma unroll
    for (int off = 1; off < 64; off <<= 1) {
        int u = __shfl_up(inc, off);
        if (lane >= off) inc += u;
    }
    if (lane == 63) ws[wid] = inc;
    __syncthreads();
    int wbase = 0;
    #pragma unroll
    for (int w = 0; w < 4; ++w) wbase += (w < wid) ? ws[w] : 0;
    if (idx < N_NODES) {
        int ex = bpre[blockIdx.x] + wbase + (inc - v);
        offsets[idx] = ex;
        wo[idx]      = ex;
    }
    if (blockIdx.x == 0 && threadIdx.x == 0) offsets[N_NODES] = N_EDGE;
}

__global__ __launch_bounds__(256) void scatter_kernel(
    const int* __restrict__ eidx, int* __restrict__ wo, int* __restrict__ sorted)
{
    int e = blockIdx.x * 256 + threadIdx.x;
    if (e < N_EDGE) {
        int pos = atomicAdd(&wo[eidx[N_EDGE + e]], 1);
        sorted[pos] = e;
    }
}

// ---------------------------------------------------------------------------
// Aggregation: one wave per dst node; lane owns channels {2l, 2l+1}.
// Per incoming edge: msg = y[src] + A[rt] @ Bj_all[src,rt]; accumulate in regs.
// Epilogue: h0 = (1+eps)*x[node] + acc   (bf16 store)
// ---------------------------------------------------------------------------
__global__ __launch_bounds__(256) void aggr_kernel(
    const float*          __restrict__ x,
    const int*            __restrict__ eidx,
    const int*            __restrict__ etype,
    const unsigned short* __restrict__ ybj,     // [N][256]: 0-127 y, 128-255 Bj
    const unsigned short* __restrict__ Ab,      // [rt][d][k]
    const int*            __restrict__ offsets,
    const int*            __restrict__ sorted,
    const float*          __restrict__ epsp,
    unsigned short*       __restrict__ h0)      // [N][128]
{
    const int lane = threadIdx.x & 63;
    const int node = blockIdx.x * 4 + (threadIdx.x >> 6);
    if (node >= N_NODES) return;

    const int beg = offsets[node], end = offsets[node + 1];
    float acc0 = 0.f, acc1 = 0.f;

    for (int i = beg; i < end; ++i) {
        const int eid = sorted[i];
        const int src = eidx[eid];
        const int rt  = etype[eid];

        short8v bj = *reinterpret_cast<const short8v*>(
            ybj + (size_t)src * 256 + 128 + rt * 8);          // wave-uniform 16B
        const unsigned short* ap = Ab + rt * 1024 + 16 * lane; // L1-resident (32KB)
        short8v a0 = *reinterpret_cast<const short8v*>(ap);
        short8v a1 = *reinterpret_cast<const short8v*>(ap + 8);
        unsigned yv = *reinterpret_cast<const unsigned*>(
            ybj + (size_t)src * 256 + 2 * lane);               // coalesced 256B

        float ad0 = 0.f, ad1 = 0.f;
        #pragma unroll
        for (int k = 0; k < 8; ++k) {
            float p = bf2f((unsigned short)bj[k]);
            ad0 += bf2f((unsigned short)a0[k]) * p;
            ad1 += bf2f((unsigned short)a1[k]) * p;
        }
        acc0 += bf2f((unsigned short)(yv & 0xffffu)) + ad0;
        acc1 += bf2f((unsigned short)(yv >> 16)) + ad1;
    }

    const float s1 = 1.0f + epsp[0];
    float2 xv = *reinterpret_cast<const float2*>(x + (size_t)node * DIM + 2 * lane);
    unsigned o = (unsigned)f2bf(s1 * xv.x + acc0)
               | ((unsigned)f2bf(s1 * xv.y + acc1) << 16);
    *reinterpret_cast<unsigned*>(h0 + (size_t)node * DIM + 2 * lane) = o;
}

// ---------------------------------------------------------------------------
// Strip GEMM: C[M x NOUT] = act(A[M x K] @ Wb[NOUT x K]^T + bias)
// One wave: 2 strips of 16 rows, all NOUT cols. A-frags in regs, B from L2.
// AMODE: 0 = A fp32, 2 = A bf16.  OMODE: 0 = bf16, 1 = bf16 relu+bias, 2 = fp32 +bias
// ---------------------------------------------------------------------------
template<int K, int NOUT, int AMODE, int OMODE>
__global__ __launch_bounds__(256) void strip_gemm(
    const void*           __restrict__ Aptr,
    const unsigned short* __restrict__ Wb,
    const float*          __restrict__ bias,
    void*                 __restrict__ Out)
{
    constexpr int NSTRIP = 2;
    constexpr int KT = K / 32;
    constexpr int NT = NOUT / 16;
    constexpr int NSTRIPS_TOT = N_NODES / 16;   // 6250

    const int wave = threadIdx.x >> 6;
    const int lane = threadIdx.x & 63;
    const int job  = blockIdx.x * 4 + wave;
    const int strip0 = job * NSTRIP;
    if (strip0 >= NSTRIPS_TOT) return;

    const int row16 = lane & 15;
    const int kgrp  = lane >> 4;

    short8v afrag[NSTRIP][KT];
    #pragma unroll
    for (int s = 0; s < NSTRIP; ++s) {
        const int m = (strip0 + s) * 16 + row16;
        #pragma unroll
        for (int kt = 0; kt < KT; ++kt) {
            const int k0 = kt * 32 + kgrp * 8;
            if constexpr (AMODE == 2) {
                afrag[s][kt] = *reinterpret_cast<const short8v*>(
                    (const unsigned short*)Aptr + (size_t)m * K + k0);
            } else {
                const float* ap = (const float*)Aptr + (size_t)m * K + k0;
                float4v v0 = *reinterpret_cast<const float4v*>(ap);
                float4v v1 = *reinterpret_cast<const float4v*>(ap + 4);
                short8v f;
                #pragma unroll
                for (int j = 0; j < 4; ++j) {
                    f[j]     = (short)f2bf(v0[j]);
                    f[4 + j] = (short)f2bf(v1[j]);
                }
                afrag[s][kt] = f;
            }
        }
    }

    #pragma unroll 2
    for (int nt = 0; nt < NT; ++nt) {
        const int n = nt * 16 + row16;
        float4v acc[NSTRIP];
        #pragma unroll
        for (int s = 0; s < NSTRIP; ++s) acc[s] = (float4v){0.f, 0.f, 0.f, 0.f};

        #pragma unroll
        for (int kt = 0; kt < KT; ++kt) {
            short8v bfrag = *reinterpret_cast<const short8v*>(
                Wb + (size_t)n * K + kt * 32 + kgrp * 8);
            #pragma unroll
            for (int s = 0; s < NSTRIP; ++s)
                acc[s] = __builtin_amdgcn_mfma_f32_16x16x32_bf16(
                    afrag[s][kt], bfrag, acc[s], 0, 0, 0);
        }

        const float bv = (OMODE != 0) ? bias[n] : 0.f;
        #pragma unroll
        for (int s = 0; s < NSTRIP; ++s) {
            #pragma unroll
            for (int r = 0; r < 4; ++r) {
                const int m = (strip0 + s) * 16 + kgrp * 4 + r;
                float v = acc[s][r];
                if constexpr (OMODE == 1) v = fmaxf(v + bv, 0.f);
                if constexpr (OMODE == 2) v = v + bv;
                if constexpr (OMODE == 2)
                    ((float*)Out)[(size_t)m * NOUT + n] = v;
                else
                    ((unsigned short*)Out)[(size_t)m * NOUT + n] = f2bf(v);
            }
        }
    }
}

// ---------------------------------------------------------------------------
// Launch
// ---------------------------------------------------------------------------
extern "C" void kernel_launch(void* const* d_in, const int* in_sizes, int n_in,
                              void* d_out, int out_size, void* d_ws, size_t ws_size,
                              hipStream_t stream)
{
    const float* x     = (const float*)d_in[0];
    const int*   eidx  = (const int*)  d_in[1];
    const int*   etype = (const int*)  d_in[2];
    const float* W     = (const float*)d_in[3];
    const float* eps   = (const float*)d_in[4];
    const float* A_emb = (const float*)d_in[5];
    const float* B_emb = (const float*)d_in[6];
    const float* W1    = (const float*)d_in[7];
    const float* b1    = (const float*)d_in[8];
    const float* W2    = (const float*)d_in[9];
    const float* b2    = (const float*)d_in[10];
    const float* W3    = (const float*)d_in[11];
    const float* b3    = (const float*)d_in[12];

    char* wsb = (char*)d_ws;
    // ws layout (lifetime-overlapped), total ~102.8 MB:
    //   [0, 51.2MB)        : ybj bf16 [N][256]   -> later h1 bf16 [N][256]
    //   [51.2MB, 76.8MB)   : h0 bf16 [N][128]    -> overwritten by h2 lower half
    //   [76.8MB, ~79MB)    : deg/offsets/wo/sorted/bsum/bpre (dead before h2 written)
    //   [51.2MB, 102.4MB)  : h2 bf16 [N][256]    (written step 9, after all above dead)
    //   [102.4MB, +360KB)  : bf16 weights/embeddings
    unsigned short* ybj  = (unsigned short*)(wsb);
    unsigned short* h1   = (unsigned short*)(wsb);
    unsigned short* h0   = (unsigned short*)(wsb + 51200000);
    unsigned short* h2   = (unsigned short*)(wsb + 51200000);
    int*            deg     = (int*)(wsb + 76800000);
    int*            offsets = (int*)(wsb + 76800000 + 400000);
    int*            wo      = (int*)(wsb + 76800000 + 800004);
    int*            sorted  = (int*)(wsb + 76800000 + 1200004);
    int*            bsum    = (int*)(wsb + 76800000 + 2200008);
    int*            bpre    = (int*)(wsb + 76800000 + 2201576);
    unsigned short* wts  = (unsigned short*)(wsb + 102400000);

    unsigned short* WyB = wts;
    unsigned short* W1b = wts + 32768;
    unsigned short* W2b = wts + 65536;
    unsigned short* W3b = wts + 131072;
    unsigned short* Ab  = wts + 163840;

    // 1) build bf16 weights / fused [W; BcatT] / A table
    wcvt_kernel<<<704, 256, 0, stream>>>(W, W1, W2, W3, A_emb, B_emb, wts);

    // 2) zero degree counters
    hipMemsetAsync(deg, 0, N_NODES * sizeof(int), stream);

    // 3) fused node GEMM: ybj[n] = [ x@W.T | x@Bcat ]   (bf16)
    strip_gemm<128, 256, 0, 0><<<782, 256, 0, stream>>>(x, WyB, nullptr, ybj);

    // 4-6) counting sort of edges by dst (two-level scan)
    hist_kernel      <<<977, 256, 0, stream>>>(eidx, deg);
    scan_part_kernel <<<SCAN_BLOCKS, 256, 0, stream>>>(deg, bsum);
    scan_bsum_kernel <<<1, 512, 0, stream>>>(bsum, bpre);
    scan_final_kernel<<<SCAN_BLOCKS, 256, 0, stream>>>(deg, bpre, offsets, wo);
    scatter_kernel   <<<977, 256, 0, stream>>>(eidx, wo, sorted);

    // 7) aggregate + GIN update -> h0 (bf16)
    aggr_kernel<<<25000, 256, 0, stream>>>(x, eidx, etype, ybj, Ab,
                                           offsets, sorted, eps, h0);

    // 8) h1 = relu(h0 @ W1.T + b1)
    strip_gemm<128, 256, 2, 1><<<782, 256, 0, stream>>>(h0, W1b, b1, h1);

    // 9) h2 = relu(h1 @ W2.T + b2)
    strip_gemm<256, 256, 2, 1><<<782, 256, 0, stream>>>(h1, W2b, b2, h2);

    // 10) out = h2 @ W3.T + b3   (fp32)
    strip_gemm<256, 128, 2, 2><<<782, 256, 0, stream>>>(h2, W3b, b3, d_out);
}

// Round 5
// 389.926 us; speedup vs baseline: 1.6599x; 1.0390x over previous
//
#include <hip/hip_runtime.h>
#include <stdint.h>

#define N_NODES 100000
#define DIM     128
#define RANK    8
#define N_REL   16
#define N_EDGE  250000

#define SCAN_BLOCKS 391   // ceil(N_NODES / 256)

typedef __attribute__((ext_vector_type(8))) short  short8v;
typedef __attribute__((ext_vector_type(4))) float  float4v;

__device__ inline unsigned short f2bf(float f) {
    union { float f; unsigned u; } v; v.f = f;
    unsigned r = v.u + 0x7fffu + ((v.u >> 16) & 1u);   // round-nearest-even
    return (unsigned short)(r >> 16);
}
__device__ inline float bf2f(unsigned short h) {
    union { unsigned u; float f; } v; v.u = ((unsigned)h) << 16;
    return v.f;
}

// ---------------------------------------------------------------------------
// Weight / embedding fp32 -> bf16 conversion + layout build (once per launch).
// Output (shorts):
//   [0,32768)       WyB [256][128] : rows 0-127 = W[out][in];
//                   rows 128+c (c=rt*8+k) : col d = B_emb[rt][d*8+k]  (BcatT)
//   [32768,65536)   W1b [256][128]
//   [65536,131072)  W2b [256][256]
//   [131072,163840) W3b [128][256]
//   [163840,180224) Ab  [rt][d][k]  (natural A_emb layout)
// ---------------------------------------------------------------------------
__global__ __launch_bounds__(256) void wcvt_kernel(
    const float* __restrict__ W,  const float* __restrict__ W1,
    const float* __restrict__ W2, const float* __restrict__ W3,
    const float* __restrict__ Ae, const float* __restrict__ Be,
    unsigned short* __restrict__ out)
{
    int i = blockIdx.x * blockDim.x + threadIdx.x;
    if (i >= 180224) return;
    float v;
    if      (i <  16384) v = W[i];
    else if (i <  32768) {
        int j = i - 16384; int c = j >> 7, d = j & 127;
        v = Be[(c >> 3) * 1024 + d * 8 + (c & 7)];
    }
    else if (i <  65536) v = W1[i - 32768];
    else if (i < 131072) v = W2[i - 65536];
    else if (i < 163840) v = W3[i - 131072];
    else                 v = Ae[i - 163840];
    out[i] = f2bf(v);
}

// ---------------------------------------------------------------------------
// Counting sort of edges by dst
// ---------------------------------------------------------------------------
__global__ __launch_bounds__(256) void hist_kernel(
    const int* __restrict__ eidx, int* __restrict__ deg)
{
    int e = blockIdx.x * 256 + threadIdx.x;
    if (e < N_EDGE) atomicAdd(&deg[eidx[N_EDGE + e]], 1);
}

// Two-level scan: partial block sums -> scan of block sums -> final scan.
__global__ __launch_bounds__(256) void scan_part_kernel(
    const int* __restrict__ deg, int* __restrict__ bsum)
{
    const int idx  = blockIdx.x * 256 + threadIdx.x;
    const int lane = threadIdx.x & 63, wid = threadIdx.x >> 6;
    __shared__ int ws[4];
    int v = (idx < N_NODES) ? deg[idx] : 0;
    #pragma unroll
    for (int off = 1; off < 64; off <<= 1) v += __shfl_xor(v, off);
    if (lane == 0) ws[wid] = v;
    __syncthreads();
    if (threadIdx.x == 0) bsum[blockIdx.x] = ws[0] + ws[1] + ws[2] + ws[3];
}

__global__ __launch_bounds__(512) void scan_bsum_kernel(
    const int* __restrict__ bsum, int* __restrict__ bpre)
{
    const int t = threadIdx.x;
    const int lane = t & 63, wid = t >> 6;
    __shared__ int ws[8];
    int v = (t < SCAN_BLOCKS) ? bsum[t] : 0;
    int inc = v;
    #pragma unroll
    for (int off = 1; off < 64; off <<= 1) {
        int u = __shfl_up(inc, off);
        if (lane >= off) inc += u;
    }
    if (lane == 63) ws[wid] = inc;
    __syncthreads();
    if (wid == 0) {
        int u = (lane < 8) ? ws[lane] : 0;
        int winc = u;
        #pragma unroll
        for (int off = 1; off < 8; off <<= 1) {
            int w = __shfl_up(winc, off);
            if (lane >= off) winc += w;
        }
        if (lane < 8) ws[lane] = winc - u;   // exclusive wave base
    }
    __syncthreads();
    if (t < SCAN_BLOCKS) bpre[t] = ws[wid] + (inc - v);
}

__global__ __launch_bounds__(256) void scan_final_kernel(
    const int* __restrict__ deg, const int* __restrict__ bpre,
    int* __restrict__ offsets, int* __restrict__ wo)
{
    const int idx  = blockIdx.x * 256 + threadIdx.x;
    const int lane = threadIdx.x & 63, wid = threadIdx.x >> 6;
    __shared__ int ws[4];
    int v = (idx < N_NODES) ? deg[idx] : 0;
    int inc = v;
    #pragma unroll
    for (int off = 1; off < 64; off <<= 1) {
        int u = __shfl_up(inc, off);
        if (lane >= off) inc += u;
    }
    if (lane == 63) ws[wid] = inc;
    __syncthreads();
    int wbase = 0;
    #pragma unroll
    for (int w = 0; w < 4; ++w) wbase += (w < wid) ? ws[w] : 0;
    if (idx < N_NODES) {
        int ex = bpre[blockIdx.x] + wbase + (inc - v);
        offsets[idx] = ex;
        wo[idx]      = ex;
    }
    if (blockIdx.x == 0 && threadIdx.x == 0) offsets[N_NODES] = N_EDGE;
}

// Scatter: sorted[pos] = src | (rt << 20)  (src < 2^17, rt < 16)
__global__ __launch_bounds__(256) void scatter_kernel(
    const int* __restrict__ eidx, const int* __restrict__ etype,
    int* __restrict__ wo, int* __restrict__ sorted)
{
    int e = blockIdx.x * 256 + threadIdx.x;
    if (e < N_EDGE) {
        int pos = atomicAdd(&wo[eidx[N_EDGE + e]], 1);
        sorted[pos] = eidx[e] | (etype[e] << 20);
    }
}

// ---------------------------------------------------------------------------
// Aggregation: one wave per dst node; lane owns channels {2l, 2l+1}.
// Per incoming edge: msg = y[src] + A[rt] @ Bj_all[src,rt]; accumulate in regs.
// Epilogue: h0 = (1+eps)*x[node] + acc   (bf16 store)
// ---------------------------------------------------------------------------
__global__ __launch_bounds__(256) void aggr_kernel(
    const float*          __restrict__ x,
    const unsigned short* __restrict__ ybj,     // [N][256]: 0-127 y, 128-255 Bj
    const unsigned short* __restrict__ Ab,      // [rt][d][k]
    const int*            __restrict__ offsets,
    const int*            __restrict__ sorted,  // packed src|rt<<20, dst-sorted
    const float*          __restrict__ epsp,
    unsigned short*       __restrict__ h0)      // [N][128]
{
    const int lane = threadIdx.x & 63;
    const int node = blockIdx.x * 4 + (threadIdx.x >> 6);
    if (node >= N_NODES) return;

    const int beg = offsets[node], end = offsets[node + 1];
    float acc0 = 0.f, acc1 = 0.f;

    for (int i = beg; i < end; ++i) {
        const unsigned p = (unsigned)sorted[i];
        const int src = p & 0xFFFFF;
        const int rt  = p >> 20;

        short8v bj = *reinterpret_cast<const short8v*>(
            ybj + (size_t)src * 256 + 128 + rt * 8);          // wave-uniform 16B
        const unsigned short* ap = Ab + rt * 1024 + 16 * lane; // L1-resident (32KB)
        short8v a0 = *reinterpret_cast<const short8v*>(ap);
        short8v a1 = *reinterpret_cast<const short8v*>(ap + 8);
        unsigned yv = *reinterpret_cast<const unsigned*>(
            ybj + (size_t)src * 256 + 2 * lane);               // coalesced 256B

        float ad0 = 0.f, ad1 = 0.f;
        #pragma unroll
        for (int k = 0; k < 8; ++k) {
            float pv = bf2f((unsigned short)bj[k]);
            ad0 += bf2f((unsigned short)a0[k]) * pv;
            ad1 += bf2f((unsigned short)a1[k]) * pv;
        }
        acc0 += bf2f((unsigned short)(yv & 0xffffu)) + ad0;
        acc1 += bf2f((unsigned short)(yv >> 16)) + ad1;
    }

    const float s1 = 1.0f + epsp[0];
    float2 xv = *reinterpret_cast<const float2*>(x + (size_t)node * DIM + 2 * lane);
    unsigned o = (unsigned)f2bf(s1 * xv.x + acc0)
               | ((unsigned)f2bf(s1 * xv.y + acc1) << 16);
    *reinterpret_cast<unsigned*>(h0 + (size_t)node * DIM + 2 * lane) = o;
}

// ---------------------------------------------------------------------------
// Weights-stationary strip GEMM: C[M x NOUT] = act(A[M x K] @ Wb[NOUT x K]^T + b)
// 512-thread blocks (8 waves). Each wave holds a 32-col x K weight slice in
// registers (loaded once) and grid-strides over 16-row M-strips streaming A.
// NOUT=256: 8 waves cover N once (1 strip/block-iter); NOUT=128: 2 strip-groups.
// AMODE: 0 = A fp32, 2 = A bf16.  OMODE: 0 = bf16, 1 = bf16 relu+bias, 2 = fp32 +bias
// ---------------------------------------------------------------------------
template<int K, int NOUT, int AMODE, int OMODE>
__global__ __launch_bounds__(512) void wsgemm(
    const void*           __restrict__ Aptr,
    const unsigned short* __restrict__ Wb,
    const float*          __restrict__ bias,
    void*                 __restrict__ Out)
{
    constexpr int KT = K / 32;
    constexpr int NSLICE = NOUT / 32;        // waves covering one strip (4 or 8)
    constexpr int SGRP = 8 / NSLICE;         // strip-groups per block (2 or 1)
    constexpr int NSTRIPS_TOT = N_NODES / 16;   // 6250

    const int lane  = threadIdx.x & 63;
    const int w     = threadIdx.x >> 6;
    const int slice = w % NSLICE;
    const int sgrp  = w / NSLICE;
    const int row16 = lane & 15;
    const int kgrp  = lane >> 4;

    // B-frags: cols slice*32 + {0,16} + row16, all of K. Register-resident.
    short8v bfrag[2][KT];
    #pragma unroll
    for (int nt = 0; nt < 2; ++nt) {
        const int n = slice * 32 + nt * 16 + row16;
        #pragma unroll
        for (int kt = 0; kt < KT; ++kt)
            bfrag[nt][kt] = *reinterpret_cast<const short8v*>(
                Wb + (size_t)n * K + kt * 32 + kgrp * 8);
    }

    float bv0 = 0.f, bv1 = 0.f;
    if constexpr (OMODE != 0) {
        bv0 = bias[slice * 32 + row16];
        bv1 = bias[slice * 32 + 16 + row16];
    }

    for (int strip = blockIdx.x * SGRP + sgrp; strip < NSTRIPS_TOT;
         strip += gridDim.x * SGRP)
    {
        const int m = strip * 16 + row16;
        short8v afrag[KT];
        #pragma unroll
        for (int kt = 0; kt < KT; ++kt) {
            const int k0 = kt * 32 + kgrp * 8;
            if constexpr (AMODE == 2) {
                afrag[kt] = *reinterpret_cast<const short8v*>(
                    (const unsigned short*)Aptr + (size_t)m * K + k0);
            } else {
                const float* ap = (const float*)Aptr + (size_t)m * K + k0;
                float4v v0 = *reinterpret_cast<const float4v*>(ap);
                float4v v1 = *reinterpret_cast<const float4v*>(ap + 4);
                short8v f;
                #pragma unroll
                for (int j = 0; j < 4; ++j) {
                    f[j]     = (short)f2bf(v0[j]);
                    f[4 + j] = (short)f2bf(v1[j]);
                }
                afrag[kt] = f;
            }
        }

        float4v acc0 = {0.f, 0.f, 0.f, 0.f};
        float4v acc1 = {0.f, 0.f, 0.f, 0.f};
        #pragma unroll
        for (int kt = 0; kt < KT; ++kt) {
            acc0 = __builtin_amdgcn_mfma_f32_16x16x32_bf16(
                afrag[kt], bfrag[0][kt], acc0, 0, 0, 0);
            acc1 = __builtin_amdgcn_mfma_f32_16x16x32_bf16(
                afrag[kt], bfrag[1][kt], acc1, 0, 0, 0);
        }

        #pragma unroll
        for (int r = 0; r < 4; ++r) {
            const int mr = strip * 16 + kgrp * 4 + r;
            float v0 = acc0[r], v1 = acc1[r];
            if constexpr (OMODE == 1) {
                v0 = fmaxf(v0 + bv0, 0.f);
                v1 = fmaxf(v1 + bv1, 0.f);
            }
            if constexpr (OMODE == 2) { v0 += bv0; v1 += bv1; }
            if constexpr (OMODE == 2) {
                ((float*)Out)[(size_t)mr * NOUT + slice * 32 + row16]      = v0;
                ((float*)Out)[(size_t)mr * NOUT + slice * 32 + 16 + row16] = v1;
            } else {
                ((unsigned short*)Out)[(size_t)mr * NOUT + slice * 32 + row16]      = f2bf(v0);
                ((unsigned short*)Out)[(size_t)mr * NOUT + slice * 32 + 16 + row16] = f2bf(v1);
            }
        }
    }
}

// ---------------------------------------------------------------------------
// Launch
// ---------------------------------------------------------------------------
extern "C" void kernel_launch(void* const* d_in, const int* in_sizes, int n_in,
                              void* d_out, int out_size, void* d_ws, size_t ws_size,
                              hipStream_t stream)
{
    const float* x     = (const float*)d_in[0];
    const int*   eidx  = (const int*)  d_in[1];
    const int*   etype = (const int*)  d_in[2];
    const float* W     = (const float*)d_in[3];
    const float* eps   = (const float*)d_in[4];
    const float* A_emb = (const float*)d_in[5];
    const float* B_emb = (const float*)d_in[6];
    const float* W1    = (const float*)d_in[7];
    const float* b1    = (const float*)d_in[8];
    const float* W2    = (const float*)d_in[9];
    const float* b2    = (const float*)d_in[10];
    const float* W3    = (const float*)d_in[11];
    const float* b3    = (const float*)d_in[12];

    char* wsb = (char*)d_ws;
    // ws layout (lifetime-overlapped), total ~102.8 MB:
    //   [0, 51.2MB)        : ybj bf16 [N][256]   -> later h1 bf16 [N][256]
    //   [51.2MB, 76.8MB)   : h0 bf16 [N][128]    -> overwritten by h2 lower half
    //   [76.8MB, ~79MB)    : deg/offsets/wo/sorted/bsum/bpre (dead before h2 written)
    //   [51.2MB, 102.4MB)  : h2 bf16 [N][256]    (written step 9, after all above dead)
    //   [102.4MB, +360KB)  : bf16 weights/embeddings
    unsigned short* ybj  = (unsigned short*)(wsb);
    unsigned short* h1   = (unsigned short*)(wsb);
    unsigned short* h0   = (unsigned short*)(wsb + 51200000);
    unsigned short* h2   = (unsigned short*)(wsb + 51200000);
    int*            deg     = (int*)(wsb + 76800000);
    int*            offsets = (int*)(wsb + 76800000 + 400000);
    int*            wo      = (int*)(wsb + 76800000 + 800004);
    int*            sorted  = (int*)(wsb + 76800000 + 1200004);
    int*            bsum    = (int*)(wsb + 76800000 + 2200008);
    int*            bpre    = (int*)(wsb + 76800000 + 2201576);
    unsigned short* wts  = (unsigned short*)(wsb + 102400000);

    unsigned short* WyB = wts;
    unsigned short* W1b = wts + 32768;
    unsigned short* W2b = wts + 65536;
    unsigned short* W3b = wts + 131072;
    unsigned short* Ab  = wts + 163840;

    // 1) build bf16 weights / fused [W; BcatT] / A table
    wcvt_kernel<<<704, 256, 0, stream>>>(W, W1, W2, W3, A_emb, B_emb, wts);

    // 2) zero degree counters
    hipMemsetAsync(deg, 0, N_NODES * sizeof(int), stream);

    // 3) fused node GEMM: ybj[n] = [ x@W.T | x@Bcat ]   (bf16)
    wsgemm<128, 256, 0, 0><<<1024, 512, 0, stream>>>(x, WyB, nullptr, ybj);

    // 4-6) counting sort of edges by dst (two-level scan)
    hist_kernel      <<<977, 256, 0, stream>>>(eidx, deg);
    scan_part_kernel <<<SCAN_BLOCKS, 256, 0, stream>>>(deg, bsum);
    scan_bsum_kernel <<<1, 512, 0, stream>>>(bsum, bpre);
    scan_final_kernel<<<SCAN_BLOCKS, 256, 0, stream>>>(deg, bpre, offsets, wo);
    scatter_kernel   <<<977, 256, 0, stream>>>(eidx, etype, wo, sorted);

    // 7) aggregate + GIN update -> h0 (bf16)
    aggr_kernel<<<25000, 256, 0, stream>>>(x, ybj, Ab, offsets, sorted, eps, h0);

    // 8) h1 = relu(h0 @ W1.T + b1)
    wsgemm<128, 256, 2, 1><<<1024, 512, 0, stream>>>(h0, W1b, b1, h1);

    // 9) h2 = relu(h1 @ W2.T + b2)
    wsgemm<256, 256, 2, 1><<<1024, 512, 0, stream>>>(h1, W2b, b2, h2);

    // 10) out = h2 @ W3.T + b3   (fp32)
    wsgemm<256, 128, 2, 2><<<1024, 512, 0, stream>>>(h2, W3b, b3, d_out);
}

// Round 6
// 330.637 us; speedup vs baseline: 1.9575x; 1.1793x over previous
//
#include <hip/hip_runtime.h>
#include <stdint.h>

#define N_NODES 100000
#define DIM     128
#define RANK    8
#define N_REL   16
#define N_EDGE  250000

#define SCAN_BLOCKS 391   // ceil(N_NODES / 256)
#define NSTRIPS     6250  // N_NODES / 16

typedef __attribute__((ext_vector_type(8))) short  short8v;
typedef __attribute__((ext_vector_type(4))) float  float4v;

__device__ inline unsigned short f2bf(float f) {
    union { float f; unsigned u; } v; v.f = f;
    unsigned r = v.u + 0x7fffu + ((v.u >> 16) & 1u);   // round-nearest-even
    return (unsigned short)(r >> 16);
}
__device__ inline float bf2f(unsigned short h) {
    union { unsigned u; float f; } v; v.u = ((unsigned)h) << 16;
    return v.f;
}

// ---------------------------------------------------------------------------
// Weight / embedding fp32 -> bf16 conversion + layout build (once per launch).
// Output (shorts):
//   [0,32768)       WyB [256][128] : rows 0-127 = W[out][in];
//                   rows 128+c (c=rt*8+k) : col d = B_emb[rt][d*8+k]  (BcatT)
//   [32768,65536)   W1b [256][128]
//   [65536,131072)  W2b [256][256]
//   [131072,163840) W3b [128][256]
//   [163840,180224) Ab  [rt][d][k]  (natural A_emb layout)
// ---------------------------------------------------------------------------
__global__ __launch_bounds__(256) void wcvt_kernel(
    const float* __restrict__ W,  const float* __restrict__ W1,
    const float* __restrict__ W2, const float* __restrict__ W3,
    const float* __restrict__ Ae, const float* __restrict__ Be,
    unsigned short* __restrict__ out)
{
    int i = blockIdx.x * blockDim.x + threadIdx.x;
    if (i >= 180224) return;
    float v;
    if      (i <  16384) v = W[i];
    else if (i <  32768) {
        int j = i - 16384; int c = j >> 7, d = j & 127;
        v = Be[(c >> 3) * 1024 + d * 8 + (c & 7)];
    }
    else if (i <  65536) v = W1[i - 32768];
    else if (i < 131072) v = W2[i - 65536];
    else if (i < 163840) v = W3[i - 131072];
    else                 v = Ae[i - 163840];
    out[i] = f2bf(v);
}

// ---------------------------------------------------------------------------
// Counting sort of edges by dst
// ---------------------------------------------------------------------------
__global__ __launch_bounds__(256) void hist_kernel(
    const int* __restrict__ eidx, int* __restrict__ deg)
{
    int e = blockIdx.x * 256 + threadIdx.x;
    if (e < N_EDGE) atomicAdd(&deg[eidx[N_EDGE + e]], 1);
}

// Two-level scan: partial block sums -> scan of block sums -> final scan.
__global__ __launch_bounds__(256) void scan_part_kernel(
    const int* __restrict__ deg, int* __restrict__ bsum)
{
    const int idx  = blockIdx.x * 256 + threadIdx.x;
    const int lane = threadIdx.x & 63, wid = threadIdx.x >> 6;
    __shared__ int ws[4];
    int v = (idx < N_NODES) ? deg[idx] : 0;
    #pragma unroll
    for (int off = 1; off < 64; off <<= 1) v += __shfl_xor(v, off);
    if (lane == 0) ws[wid] = v;
    __syncthreads();
    if (threadIdx.x == 0) bsum[blockIdx.x] = ws[0] + ws[1] + ws[2] + ws[3];
}

__global__ __launch_bounds__(512) void scan_bsum_kernel(
    const int* __restrict__ bsum, int* __restrict__ bpre)
{
    const int t = threadIdx.x;
    const int lane = t & 63, wid = t >> 6;
    __shared__ int ws[8];
    int v = (t < SCAN_BLOCKS) ? bsum[t] : 0;
    int inc = v;
    #pragma unroll
    for (int off = 1; off < 64; off <<= 1) {
        int u = __shfl_up(inc, off);
        if (lane >= off) inc += u;
    }
    if (lane == 63) ws[wid] = inc;
    __syncthreads();
    if (wid == 0) {
        int u = (lane < 8) ? ws[lane] : 0;
        int winc = u;
        #pragma unroll
        for (int off = 1; off < 8; off <<= 1) {
            int w = __shfl_up(winc, off);
            if (lane >= off) winc += w;
        }
        if (lane < 8) ws[lane] = winc - u;   // exclusive wave base
    }
    __syncthreads();
    if (t < SCAN_BLOCKS) bpre[t] = ws[wid] + (inc - v);
}

__global__ __launch_bounds__(256) void scan_final_kernel(
    const int* __restrict__ deg, const int* __restrict__ bpre,
    int* __restrict__ offsets, int* __restrict__ wo)
{
    const int idx  = blockIdx.x * 256 + threadIdx.x;
    const int lane = threadIdx.x & 63, wid = threadIdx.x >> 6;
    __shared__ int ws[4];
    int v = (idx < N_NODES) ? deg[idx] : 0;
    int inc = v;
    #pragma unroll
    for (int off = 1; off < 64; off <<= 1) {
        int u = __shfl_up(inc, off);
        if (lane >= off) inc += u;
    }
    if (lane == 63) ws[wid] = inc;
    __syncthreads();
    int wbase = 0;
    #pragma unroll
    for (int w = 0; w < 4; ++w) wbase += (w < wid) ? ws[w] : 0;
    if (idx < N_NODES) {
        int ex = bpre[blockIdx.x] + wbase + (inc - v);
        offsets[idx] = ex;
        wo[idx]      = ex;
    }
    if (blockIdx.x == 0 && threadIdx.x == 0) offsets[N_NODES] = N_EDGE;
}

// Scatter: sorted[pos] = src | (rt << 20)  (src < 2^17, rt < 16)
__global__ __launch_bounds__(256) void scatter_kernel(
    const int* __restrict__ eidx, const int* __restrict__ etype,
    int* __restrict__ wo, int* __restrict__ sorted)
{
    int e = blockIdx.x * 256 + threadIdx.x;
    if (e < N_EDGE) {
        int pos = atomicAdd(&wo[eidx[N_EDGE + e]], 1);
        sorted[pos] = eidx[e] | (etype[e] << 20);
    }
}

// ---------------------------------------------------------------------------
// Aggregation: one wave per dst node; lane owns channels {2l, 2l+1}.
// Per incoming edge: msg = y[src] + A[rt] @ Bj_all[src,rt]; accumulate in regs.
// Epilogue: h0 = (1+eps)*x[node] + acc   (bf16 store)
// ---------------------------------------------------------------------------
__global__ __launch_bounds__(256) void aggr_kernel(
    const float*          __restrict__ x,
    const unsigned short* __restrict__ ybj,     // [N][256]: 0-127 y, 128-255 Bj
    const unsigned short* __restrict__ Ab,      // [rt][d][k]
    const int*            __restrict__ offsets,
    const int*            __restrict__ sorted,  // packed src|rt<<20, dst-sorted
    const float*          __restrict__ epsp,
    unsigned short*       __restrict__ h0)      // [N][128]
{
    const int lane = threadIdx.x & 63;
    const int node = blockIdx.x * 4 + (threadIdx.x >> 6);
    if (node >= N_NODES) return;

    const int beg = offsets[node], end = offsets[node + 1];
    float acc0 = 0.f, acc1 = 0.f;

    for (int i = beg; i < end; ++i) {
        const unsigned p = (unsigned)sorted[i];
        const int src = p & 0xFFFFF;
        const int rt  = p >> 20;

        short8v bj = *reinterpret_cast<const short8v*>(
            ybj + (size_t)src * 256 + 128 + rt * 8);          // wave-uniform 16B
        const unsigned short* ap = Ab + rt * 1024 + 16 * lane; // L1-resident (32KB)
        short8v a0 = *reinterpret_cast<const short8v*>(ap);
        short8v a1 = *reinterpret_cast<const short8v*>(ap + 8);
        unsigned yv = *reinterpret_cast<const unsigned*>(
            ybj + (size_t)src * 256 + 2 * lane);               // coalesced 256B

        float ad0 = 0.f, ad1 = 0.f;
        #pragma unroll
        for (int k = 0; k < 8; ++k) {
            float pv = bf2f((unsigned short)bj[k]);
            ad0 += bf2f((unsigned short)a0[k]) * pv;
            ad1 += bf2f((unsigned short)a1[k]) * pv;
        }
        acc0 += bf2f((unsigned short)(yv & 0xffffu)) + ad0;
        acc1 += bf2f((unsigned short)(yv >> 16)) + ad1;
    }

    const float s1 = 1.0f + epsp[0];
    float2 xv = *reinterpret_cast<const float2*>(x + (size_t)node * DIM + 2 * lane);
    unsigned o = (unsigned)f2bf(s1 * xv.x + acc0)
               | ((unsigned)f2bf(s1 * xv.y + acc1) << 16);
    *reinterpret_cast<unsigned*>(h0 + (size_t)node * DIM + 2 * lane) = o;
}

// ---------------------------------------------------------------------------
// Weights-stationary strip GEMM (used only for the ybj projection).
// 512-thread blocks (8 waves); wave holds a 32-col x K weight slice in regs,
// grid-strides over 16-row M-strips. AMODE 0 = A fp32. OMODE 0 = bf16 store.
// ---------------------------------------------------------------------------
template<int K, int NOUT, int AMODE, int OMODE>
__global__ __launch_bounds__(512) void wsgemm(
    const void*           __restrict__ Aptr,
    const unsigned short* __restrict__ Wb,
    const float*          __restrict__ bias,
    void*                 __restrict__ Out)
{
    constexpr int KT = K / 32;
    constexpr int NSLICE = NOUT / 32;
    constexpr int SGRP = 8 / NSLICE;

    const int lane  = threadIdx.x & 63;
    const int w     = threadIdx.x >> 6;
    const int slice = w % NSLICE;
    const int sgrp  = w / NSLICE;
    const int row16 = lane & 15;
    const int kgrp  = lane >> 4;

    short8v bfrag[2][KT];
    #pragma unroll
    for (int nt = 0; nt < 2; ++nt) {
        const int n = slice * 32 + nt * 16 + row16;
        #pragma unroll
        for (int kt = 0; kt < KT; ++kt)
            bfrag[nt][kt] = *reinterpret_cast<const short8v*>(
                Wb + (size_t)n * K + kt * 32 + kgrp * 8);
    }

    float bv0 = 0.f, bv1 = 0.f;
    if constexpr (OMODE != 0) {
        bv0 = bias[slice * 32 + row16];
        bv1 = bias[slice * 32 + 16 + row16];
    }

    for (int strip = blockIdx.x * SGRP + sgrp; strip < NSTRIPS;
         strip += gridDim.x * SGRP)
    {
        const int m = strip * 16 + row16;
        short8v afrag[KT];
        #pragma unroll
        for (int kt = 0; kt < KT; ++kt) {
            const int k0 = kt * 32 + kgrp * 8;
            if constexpr (AMODE == 2) {
                afrag[kt] = *reinterpret_cast<const short8v*>(
                    (const unsigned short*)Aptr + (size_t)m * K + k0);
            } else {
                const float* ap = (const float*)Aptr + (size_t)m * K + k0;
                float4v v0 = *reinterpret_cast<const float4v*>(ap);
                float4v v1 = *reinterpret_cast<const float4v*>(ap + 4);
                short8v f;
                #pragma unroll
                for (int j = 0; j < 4; ++j) {
                    f[j]     = (short)f2bf(v0[j]);
                    f[4 + j] = (short)f2bf(v1[j]);
                }
                afrag[kt] = f;
            }
        }

        float4v acc0 = {0.f, 0.f, 0.f, 0.f};
        float4v acc1 = {0.f, 0.f, 0.f, 0.f};
        #pragma unroll
        for (int kt = 0; kt < KT; ++kt) {
            acc0 = __builtin_amdgcn_mfma_f32_16x16x32_bf16(
                afrag[kt], bfrag[0][kt], acc0, 0, 0, 0);
            acc1 = __builtin_amdgcn_mfma_f32_16x16x32_bf16(
                afrag[kt], bfrag[1][kt], acc1, 0, 0, 0);
        }

        #pragma unroll
        for (int r = 0; r < 4; ++r) {
            const int mr = strip * 16 + kgrp * 4 + r;
            float v0 = acc0[r], v1 = acc1[r];
            if constexpr (OMODE == 1) {
                v0 = fmaxf(v0 + bv0, 0.f);
                v1 = fmaxf(v1 + bv1, 0.f);
            }
            if constexpr (OMODE == 2) { v0 += bv0; v1 += bv1; }
            if constexpr (OMODE == 2) {
                ((float*)Out)[(size_t)mr * NOUT + slice * 32 + row16]      = v0;
                ((float*)Out)[(size_t)mr * NOUT + slice * 32 + 16 + row16] = v1;
            } else {
                ((unsigned short*)Out)[(size_t)mr * NOUT + slice * 32 + row16]      = f2bf(v0);
                ((unsigned short*)Out)[(size_t)mr * NOUT + slice * 32 + 16 + row16] = f2bf(v1);
            }
        }
    }
}

// ---------------------------------------------------------------------------
// Fused MLP: out = W3 @ relu(W2 @ relu(W1 @ h0 + b1) + b2) + b3 per 16-row strip.
// 8 waves/block; wave w holds register-resident weight slices:
//   W1 cols [32w,32w+32) x 128, W2 cols [32w,32w+32) x 256, W3 cols [16w,16w+16) x 256.
// h1/h2 pass through XOR-swizzled LDS ([16][256] bf16, dbuf). One HBM read of
// h0 (25.6MB) + one fp32 write of out (51.2MB) -- no intermediate round-trips.
// ---------------------------------------------------------------------------
__global__ __launch_bounds__(512, 2) void mlp_fused(
    const unsigned short* __restrict__ h0,    // [N][128] bf16
    const unsigned short* __restrict__ W1b,   // [256][128]
    const float*          __restrict__ b1,
    const unsigned short* __restrict__ W2b,   // [256][256]
    const float*          __restrict__ b2,
    const unsigned short* __restrict__ W3b,   // [128][256]
    const float*          __restrict__ b3,
    float*                __restrict__ out)   // [N][128] fp32
{
    __shared__ unsigned short lbuf[2][2][16 * 256];   // [dbuf][h1|h2], 32 KB

    const int lane  = threadIdx.x & 63;
    const int w     = threadIdx.x >> 6;    // 0..7
    const int row16 = lane & 15;
    const int kgrp  = lane >> 4;

    // register-resident weight slices
    short8v w1f[2][4], w2f[2][8], w3f[8];
    #pragma unroll
    for (int nt = 0; nt < 2; ++nt) {
        const int n = w * 32 + nt * 16 + row16;
        #pragma unroll
        for (int kt = 0; kt < 4; ++kt)
            w1f[nt][kt] = *reinterpret_cast<const short8v*>(
                W1b + (size_t)n * 128 + kt * 32 + kgrp * 8);
        #pragma unroll
        for (int kt = 0; kt < 8; ++kt)
            w2f[nt][kt] = *reinterpret_cast<const short8v*>(
                W2b + (size_t)n * 256 + kt * 32 + kgrp * 8);
    }
    {
        const int n = w * 16 + row16;
        #pragma unroll
        for (int kt = 0; kt < 8; ++kt)
            w3f[kt] = *reinterpret_cast<const short8v*>(
                W3b + (size_t)n * 256 + kt * 32 + kgrp * 8);
    }
    const float bv1[2] = {b1[w*32 + row16], b1[w*32 + 16 + row16]};
    const float bv2[2] = {b2[w*32 + row16], b2[w*32 + 16 + row16]};
    const float bv3    = b3[w*16 + row16];

    int p = 0;
    for (int strip = blockIdx.x; strip < NSTRIPS; strip += gridDim.x, p ^= 1) {
        // ---- stage 1: h1 = relu(h0 @ W1.T + b1) ----
        short8v af[8];
        #pragma unroll
        for (int kt = 0; kt < 4; ++kt)
            af[kt] = *reinterpret_cast<const short8v*>(
                h0 + (size_t)(strip * 16 + row16) * 128 + kt * 32 + kgrp * 8);

        float4v acc0 = {0.f,0.f,0.f,0.f}, acc1 = {0.f,0.f,0.f,0.f};
        #pragma unroll
        for (int kt = 0; kt < 4; ++kt) {
            acc0 = __builtin_amdgcn_mfma_f32_16x16x32_bf16(af[kt], w1f[0][kt], acc0, 0,0,0);
            acc1 = __builtin_amdgcn_mfma_f32_16x16x32_bf16(af[kt], w1f[1][kt], acc1, 0,0,0);
        }
        char* const l1 = (char*)&lbuf[p][0][0];
        #pragma unroll
        for (int nt = 0; nt < 2; ++nt) {
            #pragma unroll
            for (int r = 0; r < 4; ++r) {
                const int rw = kgrp * 4 + r;
                const int cb = (w * 32 + nt * 16 + row16) * 2;
                const float v = fmaxf((nt ? acc1[r] : acc0[r]) + bv1[nt], 0.f);
                *(unsigned short*)(l1 + rw * 512 + (cb ^ ((rw & 7) << 4))) = f2bf(v);
            }
        }
        __syncthreads();

        // ---- stage 2: h2 = relu(h1 @ W2.T + b2) ----
        #pragma unroll
        for (int kt = 0; kt < 8; ++kt)
            af[kt] = *reinterpret_cast<const short8v*>(
                l1 + row16 * 512 + ((kt * 64 + kgrp * 16) ^ ((row16 & 7) << 4)));

        acc0 = (float4v){0.f,0.f,0.f,0.f}; acc1 = (float4v){0.f,0.f,0.f,0.f};
        #pragma unroll
        for (int kt = 0; kt < 8; ++kt) {
            acc0 = __builtin_amdgcn_mfma_f32_16x16x32_bf16(af[kt], w2f[0][kt], acc0, 0,0,0);
            acc1 = __builtin_amdgcn_mfma_f32_16x16x32_bf16(af[kt], w2f[1][kt], acc1, 0,0,0);
        }
        char* const l2 = (char*)&lbuf[p][1][0];
        #pragma unroll
        for (int nt = 0; nt < 2; ++nt) {
            #pragma unroll
            for (int r = 0; r < 4; ++r) {
                const int rw = kgrp * 4 + r;
                const int cb = (w * 32 + nt * 16 + row16) * 2;
                const float v = fmaxf((nt ? acc1[r] : acc0[r]) + bv2[nt], 0.f);
                *(unsigned short*)(l2 + rw * 512 + (cb ^ ((rw & 7) << 4))) = f2bf(v);
            }
        }
        __syncthreads();

        // ---- stage 3: out = h2 @ W3.T + b3 (fp32) ----
        #pragma unroll
        for (int kt = 0; kt < 8; ++kt)
            af[kt] = *reinterpret_cast<const short8v*>(
                l2 + row16 * 512 + ((kt * 64 + kgrp * 16) ^ ((row16 & 7) << 4)));

        float4v a3 = {0.f,0.f,0.f,0.f};
        #pragma unroll
        for (int kt = 0; kt < 8; ++kt)
            a3 = __builtin_amdgcn_mfma_f32_16x16x32_bf16(af[kt], w3f[kt], a3, 0,0,0);

        #pragma unroll
        for (int r = 0; r < 4; ++r)
            out[(size_t)(strip * 16 + kgrp * 4 + r) * 128 + w * 16 + row16] = a3[r] + bv3;
    }
}

// ---------------------------------------------------------------------------
// Launch
// ---------------------------------------------------------------------------
extern "C" void kernel_launch(void* const* d_in, const int* in_sizes, int n_in,
                              void* d_out, int out_size, void* d_ws, size_t ws_size,
                              hipStream_t stream)
{
    const float* x     = (const float*)d_in[0];
    const int*   eidx  = (const int*)  d_in[1];
    const int*   etype = (const int*)  d_in[2];
    const float* W     = (const float*)d_in[3];
    const float* eps   = (const float*)d_in[4];
    const float* A_emb = (const float*)d_in[5];
    const float* B_emb = (const float*)d_in[6];
    const float* W1    = (const float*)d_in[7];
    const float* b1    = (const float*)d_in[8];
    const float* W2    = (const float*)d_in[9];
    const float* b2    = (const float*)d_in[10];
    const float* W3    = (const float*)d_in[11];
    const float* b3    = (const float*)d_in[12];

    char* wsb = (char*)d_ws;
    // ws layout:
    //   [0, 51.2MB)        : ybj bf16 [N][256]
    //   [51.2MB, 76.8MB)   : h0 bf16 [N][128]
    //   [76.8MB, ~79MB)    : deg/offsets/wo/sorted/bsum/bpre
    //   [102.4MB, +360KB)  : bf16 weights/embeddings
    unsigned short* ybj  = (unsigned short*)(wsb);
    unsigned short* h0   = (unsigned short*)(wsb + 51200000);
    int*            deg     = (int*)(wsb + 76800000);
    int*            offsets = (int*)(wsb + 76800000 + 400000);
    int*            wo      = (int*)(wsb + 76800000 + 800004);
    int*            sorted  = (int*)(wsb + 76800000 + 1200004);
    int*            bsum    = (int*)(wsb + 76800000 + 2200008);
    int*            bpre    = (int*)(wsb + 76800000 + 2201576);
    unsigned short* wts  = (unsigned short*)(wsb + 102400000);

    unsigned short* WyB = wts;
    unsigned short* W1b = wts + 32768;
    unsigned short* W2b = wts + 65536;
    unsigned short* W3b = wts + 131072;
    unsigned short* Ab  = wts + 163840;

    // 1) build bf16 weights / fused [W; BcatT] / A table
    wcvt_kernel<<<704, 256, 0, stream>>>(W, W1, W2, W3, A_emb, B_emb, wts);

    // 2) zero degree counters
    hipMemsetAsync(deg, 0, N_NODES * sizeof(int), stream);

    // 3) fused node GEMM: ybj[n] = [ x@W.T | x@Bcat ]   (bf16)
    wsgemm<128, 256, 0, 0><<<1024, 512, 0, stream>>>(x, WyB, nullptr, ybj);

    // 4-6) counting sort of edges by dst (two-level scan)
    hist_kernel      <<<977, 256, 0, stream>>>(eidx, deg);
    scan_part_kernel <<<SCAN_BLOCKS, 256, 0, stream>>>(deg, bsum);
    scan_bsum_kernel <<<1, 512, 0, stream>>>(bsum, bpre);
    scan_final_kernel<<<SCAN_BLOCKS, 256, 0, stream>>>(deg, bpre, offsets, wo);
    scatter_kernel   <<<977, 256, 0, stream>>>(eidx, etype, wo, sorted);

    // 7) aggregate + GIN update -> h0 (bf16)
    aggr_kernel<<<25000, 256, 0, stream>>>(x, ybj, Ab, offsets, sorted, eps, h0);

    // 8) fused MLP: out = W3 @ relu(W2 @ relu(W1 @ h0 + b1) + b2) + b3
    mlp_fused<<<1024, 512, 0, stream>>>(h0, W1b, b1, W2b, b2, W3b, b3, (float*)d_out);
}

// Round 7
// 301.138 us; speedup vs baseline: 2.1493x; 1.0980x over previous
//
#include <hip/hip_runtime.h>
#include <stdint.h>

#define N_NODES 100000
#define DIM     128
#define RANK    8
#define N_REL   16
#define N_EDGE  250000

#define SCAN_BLOCKS 391   // ceil(N_NODES / 256)
#define NSTRIPS     6250  // N_NODES / 16
#define NSTRIPS32   3125  // N_NODES / 32

typedef __attribute__((ext_vector_type(8))) short  short8v;
typedef __attribute__((ext_vector_type(4))) float  float4v;

__device__ inline unsigned short f2bf(float f) {
    union { float f; unsigned u; } v; v.f = f;
    unsigned r = v.u + 0x7fffu + ((v.u >> 16) & 1u);   // round-nearest-even
    return (unsigned short)(r >> 16);
}
__device__ inline float bf2f(unsigned short h) {
    union { unsigned u; float f; } v; v.u = ((unsigned)h) << 16;
    return v.f;
}

// ---------------------------------------------------------------------------
// Weight / embedding fp32 -> bf16 conversion + layout build (once per launch).
// Output (shorts):
//   [0,32768)       WyB [256][128] : rows 0-127 = W[out][in];
//                   rows 128+c (c=rt*8+k) : col d = B_emb[rt][d*8+k]  (BcatT)
//   [32768,65536)   W1b [256][128]
//   [65536,131072)  W2b [256][256]
//   [131072,163840) W3b [128][256]
//   [163840,180224) Ab  [rt][d][k]  (natural A_emb layout)
// ---------------------------------------------------------------------------
__global__ __launch_bounds__(256) void wcvt_kernel(
    const float* __restrict__ W,  const float* __restrict__ W1,
    const float* __restrict__ W2, const float* __restrict__ W3,
    const float* __restrict__ Ae, const float* __restrict__ Be,
    unsigned short* __restrict__ out)
{
    int i = blockIdx.x * blockDim.x + threadIdx.x;
    if (i >= 180224) return;
    float v;
    if      (i <  16384) v = W[i];
    else if (i <  32768) {
        int j = i - 16384; int c = j >> 7, d = j & 127;
        v = Be[(c >> 3) * 1024 + d * 8 + (c & 7)];
    }
    else if (i <  65536) v = W1[i - 32768];
    else if (i < 131072) v = W2[i - 65536];
    else if (i < 163840) v = W3[i - 131072];
    else                 v = Ae[i - 163840];
    out[i] = f2bf(v);
}

// ---------------------------------------------------------------------------
// Counting sort of edges by dst
// ---------------------------------------------------------------------------
__global__ __launch_bounds__(256) void hist_kernel(
    const int* __restrict__ eidx, int* __restrict__ deg)
{
    int e = blockIdx.x * 256 + threadIdx.x;
    if (e < N_EDGE) atomicAdd(&deg[eidx[N_EDGE + e]], 1);
}

// Two-level scan: partial block sums -> scan of block sums -> final scan.
__global__ __launch_bounds__(256) void scan_part_kernel(
    const int* __restrict__ deg, int* __restrict__ bsum)
{
    const int idx  = blockIdx.x * 256 + threadIdx.x;
    const int lane = threadIdx.x & 63, wid = threadIdx.x >> 6;
    __shared__ int ws[4];
    int v = (idx < N_NODES) ? deg[idx] : 0;
    #pragma unroll
    for (int off = 1; off < 64; off <<= 1) v += __shfl_xor(v, off);
    if (lane == 0) ws[wid] = v;
    __syncthreads();
    if (threadIdx.x == 0) bsum[blockIdx.x] = ws[0] + ws[1] + ws[2] + ws[3];
}

__global__ __launch_bounds__(512) void scan_bsum_kernel(
    const int* __restrict__ bsum, int* __restrict__ bpre)
{
    const int t = threadIdx.x;
    const int lane = t & 63, wid = t >> 6;
    __shared__ int ws[8];
    int v = (t < SCAN_BLOCKS) ? bsum[t] : 0;
    int inc = v;
    #pragma unroll
    for (int off = 1; off < 64; off <<= 1) {
        int u = __shfl_up(inc, off);
        if (lane >= off) inc += u;
    }
    if (lane == 63) ws[wid] = inc;
    __syncthreads();
    if (wid == 0) {
        int u = (lane < 8) ? ws[lane] : 0;
        int winc = u;
        #pragma unroll
        for (int off = 1; off < 8; off <<= 1) {
            int w = __shfl_up(winc, off);
            if (lane >= off) winc += w;
        }
        if (lane < 8) ws[lane] = winc - u;   // exclusive wave base
    }
    __syncthreads();
    if (t < SCAN_BLOCKS) bpre[t] = ws[wid] + (inc - v);
}

__global__ __launch_bounds__(256) void scan_final_kernel(
    const int* __restrict__ deg, const int* __restrict__ bpre,
    int* __restrict__ offsets, int* __restrict__ wo)
{
    const int idx  = blockIdx.x * 256 + threadIdx.x;
    const int lane = threadIdx.x & 63, wid = threadIdx.x >> 6;
    __shared__ int ws[4];
    int v = (idx < N_NODES) ? deg[idx] : 0;
    int inc = v;
    #pragma unroll
    for (int off = 1; off < 64; off <<= 1) {
        int u = __shfl_up(inc, off);
        if (lane >= off) inc += u;
    }
    if (lane == 63) ws[wid] = inc;
    __syncthreads();
    int wbase = 0;
    #pragma unroll
    for (int w = 0; w < 4; ++w) wbase += (w < wid) ? ws[w] : 0;
    if (idx < N_NODES) {
        int ex = bpre[blockIdx.x] + wbase + (inc - v);
        offsets[idx] = ex;
        wo[idx]      = ex;
    }
    if (blockIdx.x == 0 && threadIdx.x == 0) offsets[N_NODES] = N_EDGE;
}

// Scatter: sorted[pos] = src | (rt << 20)  (src < 2^17, rt < 16)
__global__ __launch_bounds__(256) void scatter_kernel(
    const int* __restrict__ eidx, const int* __restrict__ etype,
    int* __restrict__ wo, int* __restrict__ sorted)
{
    int e = blockIdx.x * 256 + threadIdx.x;
    if (e < N_EDGE) {
        int pos = atomicAdd(&wo[eidx[N_EDGE + e]], 1);
        sorted[pos] = eidx[e] | (etype[e] << 20);
    }
}

// ---------------------------------------------------------------------------
// Aggregation: one wave per dst node; lane owns channels {2l, 2l+1}.
// 1-ahead software pipeline: the next edge's packed descriptor is loaded
// before the current edge's FMA chain, so its gathers issue early.
// Epilogue: h0 = (1+eps)*x[node] + acc   (bf16 store)
// ---------------------------------------------------------------------------
__global__ __launch_bounds__(256) void aggr_kernel(
    const float*          __restrict__ x,
    const unsigned short* __restrict__ ybj,     // [N][256]: 0-127 y, 128-255 Bj
    const unsigned short* __restrict__ Ab,      // [rt][d][k]
    const int*            __restrict__ offsets,
    const int*            __restrict__ sorted,  // packed src|rt<<20, dst-sorted
    const float*          __restrict__ epsp,
    unsigned short*       __restrict__ h0)      // [N][128]
{
    const int lane = threadIdx.x & 63;
    const int node = blockIdx.x * 4 + (threadIdx.x >> 6);
    if (node >= N_NODES) return;

    const int beg = offsets[node], end = offsets[node + 1];
    float acc0 = 0.f, acc1 = 0.f;

    if (beg < end) {
        unsigned p = (unsigned)sorted[beg];
        for (int i = beg; i < end; ++i) {
            const int src = p & 0xFFFFF;
            const int rt  = p >> 20;

            // issue this edge's gathers
            short8v bj = *reinterpret_cast<const short8v*>(
                ybj + (size_t)src * 256 + 128 + rt * 8);           // wave-uniform 16B
            const unsigned short* ap = Ab + rt * 1024 + 16 * lane; // L1-resident
            short8v a0 = *reinterpret_cast<const short8v*>(ap);
            short8v a1 = *reinterpret_cast<const short8v*>(ap + 8);
            unsigned yv = *reinterpret_cast<const unsigned*>(
                ybj + (size_t)src * 256 + 2 * lane);               // coalesced 256B

            // prefetch next descriptor before consuming (hides sorted[] latency)
            const int inext = (i + 1 < end) ? (i + 1) : i;
            p = (unsigned)sorted[inext];

            float ad0 = 0.f, ad1 = 0.f;
            #pragma unroll
            for (int k = 0; k < 8; ++k) {
                float pv = bf2f((unsigned short)bj[k]);
                ad0 += bf2f((unsigned short)a0[k]) * pv;
                ad1 += bf2f((unsigned short)a1[k]) * pv;
            }
            acc0 += bf2f((unsigned short)(yv & 0xffffu)) + ad0;
            acc1 += bf2f((unsigned short)(yv >> 16)) + ad1;
        }
    }

    const float s1 = 1.0f + epsp[0];
    float2 xv = *reinterpret_cast<const float2*>(x + (size_t)node * DIM + 2 * lane);
    unsigned o = (unsigned)f2bf(s1 * xv.x + acc0)
               | ((unsigned)f2bf(s1 * xv.y + acc1) << 16);
    *reinterpret_cast<unsigned*>(h0 + (size_t)node * DIM + 2 * lane) = o;
}

// ---------------------------------------------------------------------------
// ybj projection GEMM: ybj[N][256] = x[N][128] @ WyB[256][128]^T   (bf16 out)
// 256-thread blocks (4 waves). Each wave owns 64 output cols (16 weight frags
// register-resident), so each A-fragment feeds 4 MFMAs. Grid-stride over
// 16-row strips.
// ---------------------------------------------------------------------------
__global__ __launch_bounds__(256) void ybj_gemm(
    const float*          __restrict__ x,
    const unsigned short* __restrict__ Wb,     // [256][128]
    unsigned short*       __restrict__ Out)    // [N][256]
{
    const int lane  = threadIdx.x & 63;
    const int w     = threadIdx.x >> 6;        // 0..3
    const int row16 = lane & 15;
    const int kgrp  = lane >> 4;

    short8v bfrag[4][4];
    #pragma unroll
    for (int nt = 0; nt < 4; ++nt) {
        const int n = w * 64 + nt * 16 + row16;
        #pragma unroll
        for (int kt = 0; kt < 4; ++kt)
            bfrag[nt][kt] = *reinterpret_cast<const short8v*>(
                Wb + (size_t)n * 128 + kt * 32 + kgrp * 8);
    }

    for (int s = blockIdx.x; s < NSTRIPS; s += gridDim.x) {
        const float* ap = x + (size_t)(s * 16 + row16) * 128;
        float4v v[8];
        #pragma unroll
        for (int kt = 0; kt < 4; ++kt) {
            v[2*kt]   = *reinterpret_cast<const float4v*>(ap + kt * 32 + kgrp * 8);
            v[2*kt+1] = *reinterpret_cast<const float4v*>(ap + kt * 32 + kgrp * 8 + 4);
        }
        short8v af[4];
        #pragma unroll
        for (int kt = 0; kt < 4; ++kt) {
            short8v f;
            #pragma unroll
            for (int j = 0; j < 4; ++j) {
                f[j]     = (short)f2bf(v[2*kt][j]);
                f[4 + j] = (short)f2bf(v[2*kt+1][j]);
            }
            af[kt] = f;
        }

        float4v acc[4];
        #pragma unroll
        for (int nt = 0; nt < 4; ++nt) acc[nt] = (float4v){0.f,0.f,0.f,0.f};
        #pragma unroll
        for (int kt = 0; kt < 4; ++kt) {
            #pragma unroll
            for (int nt = 0; nt < 4; ++nt)
                acc[nt] = __builtin_amdgcn_mfma_f32_16x16x32_bf16(
                    af[kt], bfrag[nt][kt], acc[nt], 0, 0, 0);
        }

        #pragma unroll
        for (int nt = 0; nt < 4; ++nt) {
            #pragma unroll
            for (int r = 0; r < 4; ++r)
                Out[(size_t)(s * 16 + kgrp * 4 + r) * 256 + w * 64 + nt * 16 + row16]
                    = f2bf(acc[nt][r]);
        }
    }
}

// ---------------------------------------------------------------------------
// Fused MLP v2: out = W3 @ relu(W2 @ relu(W1 @ h0 + b1) + b2) + b3.
// 32-row strips (two 16-row subtiles share the weight regs). 8 waves/block;
// wave w's weight slices are PINNED in registers via asm keep-alive
// (round-6 evidence: compiler demoted them and re-fetched from L2 per strip).
// h1/h2 pass through XOR-swizzled LDS ((row&15)<<4 -> worst-case 2-way = free).
// ---------------------------------------------------------------------------
__global__ __launch_bounds__(512, 2) void mlp_fused(
    const unsigned short* __restrict__ h0,    // [N][128] bf16
    const unsigned short* __restrict__ W1b,   // [256][128]
    const float*          __restrict__ b1,
    const unsigned short* __restrict__ W2b,   // [256][256]
    const float*          __restrict__ b2,
    const unsigned short* __restrict__ W3b,   // [128][256]
    const float*          __restrict__ b3,
    float*                __restrict__ out)   // [N][128] fp32
{
    __shared__ unsigned short l1s[32 * 256];  // 16 KB
    __shared__ unsigned short l2s[32 * 256];  // 16 KB

    const int lane  = threadIdx.x & 63;
    const int w     = threadIdx.x >> 6;    // 0..7
    const int row16 = lane & 15;
    const int kgrp  = lane >> 4;

    // register-resident weight slices (pinned)
    short8v w1f[2][4], w2f[2][8], w3f[8];
    #pragma unroll
    for (int nt = 0; nt < 2; ++nt) {
        const int n = w * 32 + nt * 16 + row16;
        #pragma unroll
        for (int kt = 0; kt < 4; ++kt)
            w1f[nt][kt] = *reinterpret_cast<const short8v*>(
                W1b + (size_t)n * 128 + kt * 32 + kgrp * 8);
        #pragma unroll
        for (int kt = 0; kt < 8; ++kt)
            w2f[nt][kt] = *reinterpret_cast<const short8v*>(
                W2b + (size_t)n * 256 + kt * 32 + kgrp * 8);
    }
    {
        const int n = w * 16 + row16;
        #pragma unroll
        for (int kt = 0; kt < 8; ++kt)
            w3f[kt] = *reinterpret_cast<const short8v*>(
                W3b + (size_t)n * 256 + kt * 32 + kgrp * 8);
    }
    #pragma unroll
    for (int nt = 0; nt < 2; ++nt) {
        #pragma unroll
        for (int kt = 0; kt < 4; ++kt) asm volatile("" : "+v"(w1f[nt][kt]));
        #pragma unroll
        for (int kt = 0; kt < 8; ++kt) asm volatile("" : "+v"(w2f[nt][kt]));
    }
    #pragma unroll
    for (int kt = 0; kt < 8; ++kt) asm volatile("" : "+v"(w3f[kt]));

    const float bv1[2] = {b1[w*32 + row16], b1[w*32 + 16 + row16]};
    const float bv2[2] = {b2[w*32 + row16], b2[w*32 + 16 + row16]};
    const float bv3    = b3[w*16 + row16];

    char* const l1 = (char*)l1s;
    char* const l2 = (char*)l2s;

    for (int strip = blockIdx.x; strip < NSTRIPS32; strip += gridDim.x) {
        // ---- stage 1: h1 = relu(h0 @ W1.T + b1), both 16-row subtiles ----
        short8v af[8];
        #pragma unroll
        for (int t = 0; t < 2; ++t)
            #pragma unroll
            for (int kt = 0; kt < 4; ++kt)
                af[t*4 + kt] = *reinterpret_cast<const short8v*>(
                    h0 + (size_t)(strip * 32 + t * 16 + row16) * 128 + kt * 32 + kgrp * 8);

        float4v a1acc[2][2];
        #pragma unroll
        for (int t = 0; t < 2; ++t)
            #pragma unroll
            for (int nt = 0; nt < 2; ++nt) a1acc[t][nt] = (float4v){0.f,0.f,0.f,0.f};
        #pragma unroll
        for (int t = 0; t < 2; ++t)
            #pragma unroll
            for (int kt = 0; kt < 4; ++kt) {
                a1acc[t][0] = __builtin_amdgcn_mfma_f32_16x16x32_bf16(af[t*4+kt], w1f[0][kt], a1acc[t][0], 0,0,0);
                a1acc[t][1] = __builtin_amdgcn_mfma_f32_16x16x32_bf16(af[t*4+kt], w1f[1][kt], a1acc[t][1], 0,0,0);
            }
        #pragma unroll
        for (int t = 0; t < 2; ++t)
            #pragma unroll
            for (int nt = 0; nt < 2; ++nt)
                #pragma unroll
                for (int r = 0; r < 4; ++r) {
                    const int rw = t * 16 + kgrp * 4 + r;
                    const int cb = (w * 32 + nt * 16 + row16) * 2;
                    const float v = fmaxf(a1acc[t][nt][r] + bv1[nt], 0.f);
                    *(unsigned short*)(l1 + rw * 512 + (cb ^ ((rw & 15) << 4))) = f2bf(v);
                }
        __syncthreads();

        // ---- stage 2: h2 = relu(h1 @ W2.T + b2) ----
        float4v a2acc[2][2];
        #pragma unroll
        for (int t = 0; t < 2; ++t) {
            const int rloc = t * 16 + row16;
            #pragma unroll
            for (int kt = 0; kt < 8; ++kt)
                af[kt] = *reinterpret_cast<const short8v*>(
                    l1 + rloc * 512 + ((kt * 64 + kgrp * 16) ^ ((rloc & 15) << 4)));
            a2acc[t][0] = (float4v){0.f,0.f,0.f,0.f};
            a2acc[t][1] = (float4v){0.f,0.f,0.f,0.f};
            #pragma unroll
            for (int kt = 0; kt < 8; ++kt) {
                a2acc[t][0] = __builtin_amdgcn_mfma_f32_16x16x32_bf16(af[kt], w2f[0][kt], a2acc[t][0], 0,0,0);
                a2acc[t][1] = __builtin_amdgcn_mfma_f32_16x16x32_bf16(af[kt], w2f[1][kt], a2acc[t][1], 0,0,0);
            }
        }
        #pragma unroll
        for (int t = 0; t < 2; ++t)
            #pragma unroll
            for (int nt = 0; nt < 2; ++nt)
                #pragma unroll
                for (int r = 0; r < 4; ++r) {
                    const int rw = t * 16 + kgrp * 4 + r;
                    const int cb = (w * 32 + nt * 16 + row16) * 2;
                    const float v = fmaxf(a2acc[t][nt][r] + bv2[nt], 0.f);
                    *(unsigned short*)(l2 + rw * 512 + (cb ^ ((rw & 15) << 4))) = f2bf(v);
                }
        __syncthreads();

        // ---- stage 3: out = h2 @ W3.T + b3 (fp32) ----
        #pragma unroll
        for (int t = 0; t < 2; ++t) {
            const int rloc = t * 16 + row16;
            #pragma unroll
            for (int kt = 0; kt < 8; ++kt)
                af[kt] = *reinterpret_cast<const short8v*>(
                    l2 + rloc * 512 + ((kt * 64 + kgrp * 16) ^ ((rloc & 15) << 4)));
            float4v a3 = {0.f,0.f,0.f,0.f};
            #pragma unroll
            for (int kt = 0; kt < 8; ++kt)
                a3 = __builtin_amdgcn_mfma_f32_16x16x32_bf16(af[kt], w3f[kt], a3, 0,0,0);
            #pragma unroll
            for (int r = 0; r < 4; ++r)
                out[(size_t)(strip * 32 + t * 16 + kgrp * 4 + r) * 128 + w * 16 + row16]
                    = a3[r] + bv3;
        }
    }
}

// ---------------------------------------------------------------------------
// Launch
// ---------------------------------------------------------------------------
extern "C" void kernel_launch(void* const* d_in, const int* in_sizes, int n_in,
                              void* d_out, int out_size, void* d_ws, size_t ws_size,
                              hipStream_t stream)
{
    const float* x     = (const float*)d_in[0];
    const int*   eidx  = (const int*)  d_in[1];
    const int*   etype = (const int*)  d_in[2];
    const float* W     = (const float*)d_in[3];
    const float* eps   = (const float*)d_in[4];
    const float* A_emb = (const float*)d_in[5];
    const float* B_emb = (const float*)d_in[6];
    const float* W1    = (const float*)d_in[7];
    const float* b1    = (const float*)d_in[8];
    const float* W2    = (const float*)d_in[9];
    const float* b2    = (const float*)d_in[10];
    const float* W3    = (const float*)d_in[11];
    const float* b3    = (const float*)d_in[12];

    char* wsb = (char*)d_ws;
    // ws layout:
    //   [0, 51.2MB)        : ybj bf16 [N][256]
    //   [51.2MB, 76.8MB)   : h0 bf16 [N][128]
    //   [76.8MB, ~79MB)    : deg/offsets/wo/sorted/bsum/bpre
    //   [102.4MB, +360KB)  : bf16 weights/embeddings
    unsigned short* ybj  = (unsigned short*)(wsb);
    unsigned short* h0   = (unsigned short*)(wsb + 51200000);
    int*            deg     = (int*)(wsb + 76800000);
    int*            offsets = (int*)(wsb + 76800000 + 400000);
    int*            wo      = (int*)(wsb + 76800000 + 800004);
    int*            sorted  = (int*)(wsb + 76800000 + 1200004);
    int*            bsum    = (int*)(wsb + 76800000 + 2200008);
    int*            bpre    = (int*)(wsb + 76800000 + 2201576);
    unsigned short* wts  = (unsigned short*)(wsb + 102400000);

    unsigned short* WyB = wts;
    unsigned short* W1b = wts + 32768;
    unsigned short* W2b = wts + 65536;
    unsigned short* W3b = wts + 131072;
    unsigned short* Ab  = wts + 163840;

    // 1) build bf16 weights / fused [W; BcatT] / A table
    wcvt_kernel<<<704, 256, 0, stream>>>(W, W1, W2, W3, A_emb, B_emb, wts);

    // 2) zero degree counters
    hipMemsetAsync(deg, 0, N_NODES * sizeof(int), stream);

    // 3) fused node GEMM: ybj[n] = [ x@W.T | x@Bcat ]   (bf16)
    ybj_gemm<<<1024, 256, 0, stream>>>(x, WyB, ybj);

    // 4-6) counting sort of edges by dst (two-level scan)
    hist_kernel      <<<977, 256, 0, stream>>>(eidx, deg);
    scan_part_kernel <<<SCAN_BLOCKS, 256, 0, stream>>>(deg, bsum);
    scan_bsum_kernel <<<1, 512, 0, stream>>>(bsum, bpre);
    scan_final_kernel<<<SCAN_BLOCKS, 256, 0, stream>>>(deg, bpre, offsets, wo);
    scatter_kernel   <<<977, 256, 0, stream>>>(eidx, etype, wo, sorted);

    // 7) aggregate + GIN update -> h0 (bf16)
    aggr_kernel<<<25000, 256, 0, stream>>>(x, ybj, Ab, offsets, sorted, eps, h0);

    // 8) fused MLP: out = W3 @ relu(W2 @ relu(W1 @ h0 + b1) + b2) + b3
    mlp_fused<<<512, 512, 0, stream>>>(h0, W1b, b1, W2b, b2, W3b, b3, (float*)d_out);
}